// Round 11
// baseline (14393.134 us; speedup 1.0000x reference)
//
#include <hip/hip_runtime.h>
#include <hip/hip_bf16.h>

#define B_DIM 256
#define T_DIM 512
#define IN_DIM 1024
#define HID_DIM 1024
#define BLK 16384

typedef __attribute__((ext_vector_type(8))) short bf16x8;
typedef __attribute__((ext_vector_type(4))) float f32x4;

__device__ __forceinline__ unsigned short f2bf(float v) {
  unsigned int u = __float_as_uint(v);
  unsigned int r = (u + 0x7fffu + ((u >> 16) & 1u)) >> 16;
  return (unsigned short)r;
}

typedef __attribute__((address_space(3))) unsigned int lds_uint;
typedef const __attribute__((address_space(1))) unsigned int g_uint;
__device__ __forceinline__ void gload_lds16(const void* g, void* l) {
  __builtin_amdgcn_global_load_lds((g_uint*)g, (lds_uint*)l, 16, 0, 0);
}
// 2KB: src includes per-lane offset; dst is wave-uniform base.
__device__ __forceinline__ void glds2(const unsigned char* s, unsigned char* d) {
  gload_lds16(s, d);
  gload_lds16(s + 1024, d + 1024);
}

#define WAITVM(N) asm volatile("s_waitcnt vmcnt(" #N ")" ::: "memory")

// ---------------------------------------------------------------------------
// Pack W (4 gates, f32 [2048][1024]) -> bf16 swizzled blocks.
// Packed col in a 64-col block: g*16 + h_in. Block (cb, kc): [col 64][k' 128],
// byte = (col*256 + k'*2) ^ ((col&7)<<4). kc 0..7 = x rows, 8..15 = h rows.
// ---------------------------------------------------------------------------
__global__ void prep_pack_w(const float* __restrict__ Wi, const float* __restrict__ Wf,
                            const float* __restrict__ Wo, const float* __restrict__ Wc,
                            unsigned char* __restrict__ Wp) {
  const int bid = blockIdx.x;          // cb*16 + kc
  const int cb = bid >> 4, kc = bid & 15;
  const int tid = threadIdx.x;
  const int col = tid & 63;
  const int g = col >> 4, h_in = col & 15;
  const int kq = tid >> 6;
  const float* W = (g == 0) ? Wi : (g == 1) ? Wf : (g == 2) ? Wo : Wc;
  const float* src = W + (size_t)(kc * 128 + kq * 32) * HID_DIM + cb * 16 + h_in;
  unsigned char* dst = Wp + (size_t)bid * BLK;
  const unsigned int xo = (unsigned int)((col & 7) << 4);
#pragma unroll
  for (int b4 = 0; b4 < 4; ++b4) {
    unsigned short u[8];
#pragma unroll
    for (int j = 0; j < 8; ++j)
      u[j] = f2bf(src[(size_t)(b4 * 8 + j) * HID_DIM]);
    uint4 pk;
    pk.x = (unsigned)u[0] | ((unsigned)u[1] << 16);
    pk.y = (unsigned)u[2] | ((unsigned)u[3] << 16);
    pk.z = (unsigned)u[4] | ((unsigned)u[5] << 16);
    pk.w = (unsigned)u[6] | ((unsigned)u[7] << 16);
    unsigned int byte = ((unsigned int)(col * 256 + kq * 64 + b4 * 16)) ^ xo;
    *(uint4*)(dst + byte) = pk;
  }
}

__global__ void prep_bias(const float* __restrict__ bi, const float* __restrict__ bf_,
                          const float* __restrict__ bo, const float* __restrict__ bc,
                          float* __restrict__ bp) {
  int p = blockIdx.x * 256 + threadIdx.x;  // 0..4095
  int cbb = p >> 6, col = p & 63, g = col >> 4, h_in = col & 15;
  const float* b = (g == 0) ? bi : (g == 1) ? bf_ : (g == 2) ? bo : bc;
  bp[p] = b[cbb * 16 + h_in];
}

// ---------------------------------------------------------------------------
// Single persistent fused LSTM. 256 WGs (1/CU) x 512 thr (8 waves), coop.
// LDS 128KB: seq ring 64KB [0,64K) (gates0/1 overlay) + bulk 2x32KB pair bufs
// [64K,128K) (gatesB0/B1 overlay). Per step t (loop t=-1..511):
//   1. bulk: Gx[t+1] = x_{t+1}@Wx  (x f32 read+cvt, ds_write-staged, split-K
//      GEMM with register Wx frags; result -> 8 f32 regs via gatesB exchange)
//   2. flag wait (per-WG flag slots, wave0 parallel poll + acquire)  [t>0]
//   3. seq: h_{t-1}@Wh (r10-proven phases, register Wh frags)        [t>0]
//   4. gates exchange + epilogue (gates0+gates1 + bias + gxv regs)   [t>=0]
//   5. h store (swizzled bf16 image ring-3) + flag release store
// Bulk sits in the flag release->visible latency window -> sync hidden.
// ---------------------------------------------------------------------------
__global__ __launch_bounds__(512, 1) void lstm_one(
    const float* __restrict__ x, const unsigned char* __restrict__ Wq,
    const float* __restrict__ bp, unsigned char* hring,
    unsigned int* flags, float* __restrict__ out) {
  extern __shared__ unsigned char ring[];
  unsigned char* seqring = ring;            // 64KB
  unsigned char* bulkring = ring + 65536;   // 64KB (2 pair bufs of 32KB)
  const int wg = blockIdx.x, mb = wg >> 6, cb = wg & 63;
  const int tid = threadIdx.x, lane = tid & 63, w = tid >> 6;
  const int cg = w & 3, kh = w >> 2;        // cols cg*16..+15, chunks kh*4..+3
  const int fr = lane & 15;
  const unsigned koff2 = (unsigned)((lane >> 4) << 4);
  const int rsub = (lane >> 4) * 4;
  const int cl = cg * 16 + fr;
  // bulk staging mapping: 64 rows x 8 segs of 32 f32
  const int srow = tid >> 3;
  const int s32 = (tid & 7) * 32;

  bf16x8 BregH[4][4], BregX[4][4];
#pragma unroll
  for (int kcl = 0; kcl < 4; ++kcl)
#pragma unroll
    for (int ks = 0; ks < 4; ++ks) {
      const unsigned sw = (((unsigned)cl * 256 + (unsigned)ks * 64 + koff2) ^
                           ((unsigned)((cl & 7) << 4)));
      BregH[kcl][ks] = *(const bf16x8*)(
          Wq + ((size_t)(cb * 16 + 8 + kh * 4 + kcl) << 14) + sw);
      BregX[kcl][ks] = *(const bf16x8*)(
          Wq + ((size_t)(cb * 16 + kh * 4 + kcl) << 14) + sw);
    }
#pragma unroll
  for (int kcl = 0; kcl < 4; ++kcl)
#pragma unroll
    for (int ks = 0; ks < 4; ++ks) {
      asm volatile("" : "+v"(BregH[kcl][ks]));
      asm volatile("" : "+v"(BregX[kcl][ks]));
    }

  const int erow = tid & 63, hb2 = (tid >> 6) * 2;
  const size_t gidx = (size_t)(mb * 64 + erow) * HID_DIM + cb * 16 + hb2;
  float bI[2], bF[2], bO[2], bG[2];
#pragma unroll
  for (int j = 0; j < 2; ++j) {
    bI[j] = bp[cb * 64 + hb2 + j];
    bF[j] = bp[cb * 64 + 16 + hb2 + j];
    bO[j] = bp[cb * 64 + 32 + hb2 + j];
    bG[j] = bp[cb * 64 + 48 + hb2 + j];
  }
  float cr[2] = {0.f, 0.f};
  float gxv[8], gxn[8];
#pragma unroll
  for (int i = 0; i < 8; ++i) gxv[i] = 0.f;

  float* gates0 = (float*)seqring;             // overlay seq bufs 0-1
  float* gates1 = (float*)(seqring + 32768);   // overlay seq bufs 2-3
  float* gatesB0 = (float*)bulkring;           // overlay bulk buf 0
  float* gatesB1 = (float*)(bulkring + 32768); // overlay bulk buf 1

  auto stage_pair = [&](int t1, int p) {
    const float* src = x + ((size_t)(mb * 64 + srow) * T_DIM + t1) * IN_DIM +
                       p * 256 + s32;
    unsigned char* dbuf = bulkring + (p & 1) * 32768;
    const unsigned swz = (unsigned)((srow & 7) << 4);
#pragma unroll
    for (int c4 = 0; c4 < 4; ++c4) {
      float4 f0 = *(const float4*)(src + c4 * 8);
      float4 f1 = *(const float4*)(src + c4 * 8 + 4);
      unsigned kk = (unsigned)(s32 + c4 * 8);
      unsigned byte = ((kk >> 7) * 16384u) +
                      ((((unsigned)srow * 256u + (kk & 127u) * 2u)) ^ swz);
      uint4 pk;
      pk.x = (unsigned)f2bf(f0.x) | ((unsigned)f2bf(f0.y) << 16);
      pk.y = (unsigned)f2bf(f0.z) | ((unsigned)f2bf(f0.w) << 16);
      pk.z = (unsigned)f2bf(f1.x) | ((unsigned)f2bf(f1.y) << 16);
      pk.w = (unsigned)f2bf(f1.z) | ((unsigned)f2bf(f1.w) << 16);
      *(uint4*)(dbuf + byte) = pk;
    }
  };

  auto phases = [&](const unsigned char* Abase, f32x4* acc) {
#pragma unroll
    for (int c = 0; c < 4; ++c)
      glds2(Abase + (size_t)c * BLK, seqring + c * 16384 + w * 2048);
#pragma unroll
    for (int kc = 0; kc < 8; ++kc) {
      if (kc <= 4) WAITVM(6);
      else if (kc == 5) WAITVM(4);
      else if (kc == 6) WAITVM(2);
      else WAITVM(0);
      __builtin_amdgcn_s_barrier();
      if ((kc >> 2) == kh) {
        const int kcl = kc & 3;
        const unsigned char* Ab = seqring + (kc & 3) * 16384;
#pragma unroll
        for (int ks = 0; ks < 4; ++ks) {
          const unsigned kb = (unsigned)ks * 64 + koff2;
#pragma unroll
          for (int rb = 0; rb < 4; ++rb) {
            const unsigned r0 = (unsigned)(rb * 16 + fr);
            bf16x8 a0 = *(const bf16x8*)(Ab + ((r0 * 256 + kb) ^ ((r0 & 7) << 4)));
            acc[rb] = __builtin_amdgcn_mfma_f32_16x16x32_bf16(
                a0, BregH[kcl][ks], acc[rb], 0, 0, 0);
          }
        }
      }
      __builtin_amdgcn_s_barrier();
      if (kc + 4 < 8)
        glds2(Abase + (size_t)(kc + 4) * BLK, seqring + (kc & 3) * 16384 + w * 2048);
    }
  };

#pragma unroll 1
  for (int t = -1; t < T_DIM; ++t) {
    // keep both W fragment sets pinned (no remat)
#pragma unroll
    for (int kcl = 0; kcl < 4; ++kcl)
#pragma unroll
      for (int ks = 0; ks < 4; ++ks) {
        asm volatile("" : "+v"(BregH[kcl][ks]));
        asm volatile("" : "+v"(BregX[kcl][ks]));
      }

    // ---- 1. bulk: Gx for step t+1 (own tile; stays on-CU) ----
    const bool bulkAct = (t < T_DIM - 1);
    if (bulkAct) {
      f32x4 accB[4] = {{0.f,0.f,0.f,0.f},{0.f,0.f,0.f,0.f},
                       {0.f,0.f,0.f,0.f},{0.f,0.f,0.f,0.f}};
      stage_pair(t + 1, 0);
      __syncthreads();
#pragma unroll
      for (int p = 0; p < 4; ++p) {
        if (p < 3) stage_pair(t + 1, p + 1);
#pragma unroll
        for (int ci = 0; ci < 2; ++ci) {
          const int c = p * 2 + ci;
          if ((c >> 2) == kh) {
            const int kcl = c & 3;
            const unsigned char* Ab = bulkring + (p & 1) * 32768 + ci * 16384;
#pragma unroll
            for (int ks = 0; ks < 4; ++ks) {
              const unsigned kb = (unsigned)ks * 64 + koff2;
#pragma unroll
              for (int rb = 0; rb < 4; ++rb) {
                const unsigned r0 = (unsigned)(rb * 16 + fr);
                bf16x8 a0 = *(const bf16x8*)(Ab + ((r0 * 256 + kb) ^ ((r0 & 7) << 4)));
                accB[rb] = __builtin_amdgcn_mfma_f32_16x16x32_bf16(
                    a0, BregX[kcl][ks], accB[rb], 0, 0, 0);
              }
            }
          }
        }
        __syncthreads();
      }
      // bulk exchange -> gxn regs
      {
        float* g_ = kh ? gatesB1 : gatesB0;
#pragma unroll
        for (int rb = 0; rb < 4; ++rb)
#pragma unroll
          for (int j = 0; j < 4; ++j)
            g_[(rb * 16 + rsub + j) * 65 + cg * 16 + fr] = accB[rb][j];
      }
      __syncthreads();
#pragma unroll
      for (int g = 0; g < 4; ++g)
#pragma unroll
        for (int j = 0; j < 2; ++j)
          gxn[g * 2 + j] = gatesB0[erow * 65 + g * 16 + hb2 + j] +
                           gatesB1[erow * 65 + g * 16 + hb2 + j];
      __syncthreads();  // gatesB reads done before next step's staging
    }

    if (t >= 0) {
      f32x4 acc[4] = {{0.f,0.f,0.f,0.f},{0.f,0.f,0.f,0.f},
                      {0.f,0.f,0.f,0.f},{0.f,0.f,0.f,0.f}};
      // ---- 2. flag wait ----
      if (t > 0) {
        if (w == 0) {
          unsigned int* fl = &flags[mb * 64 + lane];
          while (!__all(__hip_atomic_load(fl, __ATOMIC_RELAXED,
                                          __HIP_MEMORY_SCOPE_AGENT) >= (unsigned)t))
            __builtin_amdgcn_s_sleep(2);
          (void)__hip_atomic_load(fl, __ATOMIC_ACQUIRE,
                                  __HIP_MEMORY_SCOPE_AGENT);  // L1/L2 invalidate
        }
        __syncthreads();
        // ---- 3. seq h GEMM ----
        const unsigned char* hA = hring + (size_t)((t + 2) % 3) * 524288 +
                                  (size_t)(mb * 8) * BLK + w * 2048 + lane * 16;
        phases(hA, acc);
      }
      // ---- 4. exchange + epilogue ----
      {
        float* g_ = kh ? gates1 : gates0;
#pragma unroll
        for (int rb = 0; rb < 4; ++rb)
#pragma unroll
          for (int j = 0; j < 4; ++j)
            g_[(rb * 16 + rsub + j) * 65 + cg * 16 + fr] = acc[rb][j];
      }
      __syncthreads();
      float hv[2];
#pragma unroll
      for (int j = 0; j < 2; ++j) {
        int hc = hb2 + j;
        float pi = gates0[erow * 65 + hc]      + gates1[erow * 65 + hc]      + bI[j] + gxv[0 + j];
        float pf = gates0[erow * 65 + 16 + hc] + gates1[erow * 65 + 16 + hc] + bF[j] + gxv[2 + j];
        float po = gates0[erow * 65 + 32 + hc] + gates1[erow * 65 + 32 + hc] + bO[j] + gxv[4 + j];
        float pg = gates0[erow * 65 + 48 + hc] + gates1[erow * 65 + 48 + hc] + bG[j] + gxv[6 + j];
        float ig = 1.f / (1.f + __expf(-pi));
        float fg = 1.f / (1.f + __expf(-pf));
        float og = 1.f / (1.f + __expf(-po));
        float gg = 1.f - 2.f / (1.f + __expf(2.f * pg));  // tanh
        float cn = fg * cr[j] + ig * gg;
        cr[j] = cn;
        hv[j] = og * (1.f - 2.f / (1.f + __expf(2.f * cn)));
      }
      // ---- 5. h store + flag release ----
      if (t < T_DIM - 1) {
        int hcg = cb * 16 + hb2;
        int kc2 = hcg >> 7, kp = hcg & 127;
        unsigned byte = ((unsigned)(erow * 256 + kp * 2)) ^ ((unsigned)((erow & 7) << 4));
        unsigned pk = (unsigned)f2bf(hv[0]) | ((unsigned)f2bf(hv[1]) << 16);
        unsigned int* hd = (unsigned int*)(hring + (size_t)(t % 3) * 524288 +
                                           (size_t)(mb * 8 + kc2) * BLK + byte);
        __hip_atomic_store(hd, pk, __ATOMIC_RELAXED, __HIP_MEMORY_SCOPE_AGENT);
      }
      WAITVM(0);        // per-wave: h store drained before barrier
      __syncthreads();  // all waves done (stores + gates reads)
      if (tid == 0 && t < T_DIM - 1)
        __hip_atomic_store(&flags[mb * 64 + cb], (unsigned)(t + 1),
                           __ATOMIC_RELEASE, __HIP_MEMORY_SCOPE_AGENT);
      if (t == T_DIM - 1) {
        *(float2*)(out + gidx) = make_float2(hv[0], hv[1]);
        *(float2*)(out + (size_t)B_DIM * HID_DIM + gidx) = make_float2(cr[0], cr[1]);
      }
    }
    // carry Gx regs to next step
#pragma unroll
    for (int i = 0; i < 8; ++i) gxv[i] = gxn[i];
  }
}

extern "C" void kernel_launch(void* const* d_in, const int* in_sizes, int n_in,
                              void* d_out, int out_size, void* d_ws, size_t ws_size,
                              hipStream_t stream) {
  (void)in_sizes; (void)n_in; (void)out_size;
  const float* x   = (const float*)d_in[0];
  const float* Wf_ = (const float*)d_in[1];
  const float* bf_ = (const float*)d_in[2];
  const float* Wi_ = (const float*)d_in[3];
  const float* bi_ = (const float*)d_in[4];
  const float* Wo_ = (const float*)d_in[5];
  const float* bo_ = (const float*)d_in[6];
  const float* Wc_ = (const float*)d_in[7];
  const float* bc_ = (const float*)d_in[8];
  float* out = (float*)d_out;
  unsigned char* ws = (unsigned char*)d_ws;

  unsigned char* Wp = ws;
  size_t off = 16777216;
  float* bp = (float*)(ws + off);                    off += 16384;
  unsigned int* flags = (unsigned int*)(ws + off);   off += 8192;
  off += 8192;  // pad
  unsigned char* hring = ws + off;                   off += 3 * 524288;
  if (ws_size < off) return;  // ~18.4 MB, trivially available

  prep_pack_w<<<1024, 256, 0, stream>>>(Wi_, Wf_, Wo_, Wc_, Wp);
  prep_bias<<<16, 256, 0, stream>>>(bi_, bf_, bo_, bc_, bp);
  hipMemsetAsync(flags, 0, 8192, stream);

  hipFuncSetAttribute((const void*)lstm_one,
                      hipFuncAttributeMaxDynamicSharedMemorySize, 131072);
  const float* a_x = x;
  const unsigned char* a_wp = Wp;
  const float* a_bp = bp;
  unsigned char* a_hr = hring;
  unsigned int* a_fl = flags;
  float* a_out = out;
  void* args[] = {&a_x, &a_wp, &a_bp, &a_hr, &a_fl, &a_out};
  hipLaunchCooperativeKernel((const void*)lstm_one, dim3(256), dim3(512),
                             args, 131072u, stream);
}

// Round 12
// 9738.461 us; speedup vs baseline: 1.4780x; 1.4780x over previous
//
#include <hip/hip_runtime.h>
#include <hip/hip_bf16.h>

#define B_DIM 256
#define T_DIM 512
#define WINT 32
#define NWIN 16
#define IN_DIM 1024
#define HID_DIM 1024
#define BLK 16384

typedef __attribute__((ext_vector_type(8))) short bf16x8;
typedef __attribute__((ext_vector_type(4))) float f32x4;

__device__ __forceinline__ unsigned short f2bf(float v) {
  unsigned int u = __float_as_uint(v);
  unsigned int r = (u + 0x7fffu + ((u >> 16) & 1u)) >> 16;
  return (unsigned short)r;
}
__device__ __forceinline__ float bflo(unsigned u) { return __uint_as_float(u << 16); }
__device__ __forceinline__ float bfhi(unsigned u) { return __uint_as_float(u & 0xffff0000u); }

typedef __attribute__((address_space(3))) unsigned int lds_uint;
typedef const __attribute__((address_space(1))) unsigned int g_uint;
__device__ __forceinline__ void gload_lds16(const void* g, void* l) {
  __builtin_amdgcn_global_load_lds((g_uint*)g, (lds_uint*)l, 16, 0, 0);
}
// 2KB: src includes per-lane offset; dst is wave-uniform base.
__device__ __forceinline__ void glds2(const unsigned char* s, unsigned char* d) {
  gload_lds16(s, d);
  gload_lds16(s + 1024, d + 1024);
}

#define WAITVM(N) asm volatile("s_waitcnt vmcnt(" #N ")" ::: "memory")

// ---------------------------------------------------------------------------
// Pack W (4 gates, f32 [2048][1024]) -> bf16 swizzled blocks.
// Packed col in a 64-col block: g*16 + h_in. Block (cb, kc): [col 64][k' 128],
// byte = (col*256 + k'*2) ^ ((col&7)<<4). kc 0..7 = x rows, 8..15 = h rows.
// ---------------------------------------------------------------------------
__global__ void prep_pack_w(const float* __restrict__ Wi, const float* __restrict__ Wf,
                            const float* __restrict__ Wo, const float* __restrict__ Wc,
                            unsigned char* __restrict__ Wp) {
  const int bid = blockIdx.x;          // cb*16 + kc
  const int cb = bid >> 4, kc = bid & 15;
  const int tid = threadIdx.x;
  const int col = tid & 63;
  const int g = col >> 4, h_in = col & 15;
  const int kq = tid >> 6;
  const float* W = (g == 0) ? Wi : (g == 1) ? Wf : (g == 2) ? Wo : Wc;
  const float* src = W + (size_t)(kc * 128 + kq * 32) * HID_DIM + cb * 16 + h_in;
  unsigned char* dst = Wp + (size_t)bid * BLK;
  const unsigned int xo = (unsigned int)((col & 7) << 4);
#pragma unroll
  for (int b4 = 0; b4 < 4; ++b4) {
    unsigned short u[8];
#pragma unroll
    for (int j = 0; j < 8; ++j)
      u[j] = f2bf(src[(size_t)(b4 * 8 + j) * HID_DIM]);
    uint4 pk;
    pk.x = (unsigned)u[0] | ((unsigned)u[1] << 16);
    pk.y = (unsigned)u[2] | ((unsigned)u[3] << 16);
    pk.z = (unsigned)u[4] | ((unsigned)u[5] << 16);
    pk.w = (unsigned)u[6] | ((unsigned)u[7] << 16);
    unsigned int byte = ((unsigned int)(col * 256 + kq * 64 + b4 * 16)) ^ xo;
    *(uint4*)(dst + byte) = pk;
  }
}

__global__ void prep_bias(const float* __restrict__ bi, const float* __restrict__ bf_,
                          const float* __restrict__ bo, const float* __restrict__ bc,
                          float* __restrict__ bp) {
  int p = blockIdx.x * 256 + threadIdx.x;  // 0..4095
  int cbb = p >> 6, col = p & 63, g = col >> 4, h_in = col & 15;
  const float* b = (g == 0) ? bi : (g == 1) ? bf_ : (g == 2) ? bo : bc;
  bp[p] = b[cbb * 16 + h_in];
}

// Pack one WINT-step window of x -> bf16 swizzled blocks (tw,mb,kc) = bid.
__global__ void prep_pack_x_win(const float* __restrict__ x,
                                unsigned char* __restrict__ xpw, int t0) {
  const int bid = blockIdx.x;               // (tw*4+mb)*8+kc, WINT*32 blocks
  const int kc = bid & 7, mb = (bid >> 3) & 3, tw = bid >> 5;
  const int tid = threadIdx.x;
  const int row = tid >> 2, kseg = tid & 3;
  const float* src = x + ((size_t)(mb * 64 + row) * T_DIM + (t0 + tw)) * IN_DIM +
                     kc * 128 + kseg * 32;
  unsigned char* dst = xpw + (size_t)bid * BLK;
  const unsigned int xo = (unsigned)((row & 7) << 4);
#pragma unroll
  for (int c4 = 0; c4 < 4; ++c4) {
    float4 f0 = *(const float4*)(src + c4 * 8);
    float4 f1 = *(const float4*)(src + c4 * 8 + 4);
    uint4 pk;
    pk.x = (unsigned)f2bf(f0.x) | ((unsigned)f2bf(f0.y) << 16);
    pk.y = (unsigned)f2bf(f0.z) | ((unsigned)f2bf(f0.w) << 16);
    pk.z = (unsigned)f2bf(f1.x) | ((unsigned)f2bf(f1.y) << 16);
    pk.w = (unsigned)f2bf(f1.z) | ((unsigned)f2bf(f1.w) << 16);
    *(uint4*)(dst + (((unsigned)(row * 256 + kseg * 64 + c4 * 16)) ^ xo)) = pk;
  }
}

// ---------------------------------------------------------------------------
// Fused window kernel, templated on LDS ring depth RN (RN*16KB + overlays).
// RN=3 (48KB) -> 2 blocks/CU co-residency for mode 0; RN=4 (64KB) = proven
// r10 config for fallback/prefill.
// mode 0: 512 WGs (0-255 seq win w, 256-511 bulk win w+1); mode 1: seq only;
// mode 2: bulk only (prefill, non-coop). 64x64 tile, 8 waves (cg cols 16,
// kh K-half), Breg[4][4]=64 VGPR pinned; A staged RN-deep LDS ring via
// global_load_lds, counted vmcnt. Seq: A = h image (ring-3 global, per-WG
// flag stores + wave0 parallel poll). Bulk: A = packed x -> packed Gx bf16.
// ---------------------------------------------------------------------------
template <int RN>
__global__ __launch_bounds__(512, 2) void lstm_fused(
    const unsigned char* __restrict__ gxCur, const unsigned char* __restrict__ xpNext,
    const unsigned char* __restrict__ Wq, const float* __restrict__ bp,
    unsigned char* __restrict__ gxNext, unsigned char* hring,
    unsigned int* flags, float* cst, float* __restrict__ out,
    int t0, int mode) {
  extern __shared__ unsigned char ring[];  // RN x 16KB chunk bufs
  const int tid = threadIdx.x, lane = tid & 63, w = tid >> 6;
  const int cg = w & 3, kh = w >> 2;
  const int fr = lane & 15;
  const unsigned koff2 = (unsigned)((lane >> 4) << 4);
  const int rsub = (lane >> 4) * 4;
  const int cl = cg * 16 + fr;

  bool isSeq; int wg;
  if (mode == 0) {
    isSeq = (int)blockIdx.x < 256;
    wg = isSeq ? (int)blockIdx.x : (int)blockIdx.x - 256;
  } else {
    isSeq = (mode == 1);
    wg = (int)blockIdx.x;
  }
  const int mb = (wg >> 6) & 3, cb = wg & 63;

  bf16x8 Breg[4][4];
  {
    const int xoff = isSeq ? 8 : 0;  // h rows live at kc 8..15, x rows 0..7
#pragma unroll
    for (int kcl = 0; kcl < 4; ++kcl)
#pragma unroll
      for (int ks = 0; ks < 4; ++ks)
        Breg[kcl][ks] = *(const bf16x8*)(
            Wq + ((size_t)(cb * 16 + xoff + kh * 4 + kcl) << 14) +
            (((unsigned)cl * 256 + (unsigned)ks * 64 + koff2) ^
             ((unsigned)((cl & 7) << 4))));
#pragma unroll
    for (int kcl = 0; kcl < 4; ++kcl)
#pragma unroll
      for (int ks = 0; ks < 4; ++ks)
        asm volatile("" : "+v"(Breg[kcl][ks]));
  }

  // gates overlays: RN=4 keeps the proven 32768 split; RN=3 packs at +16640
  float* gates0 = (float*)ring;
  float* gates1 = (float*)(ring + (RN == 4 ? 32768 : 16640));

  auto phases = [&](const unsigned char* Abase, f32x4* acc) {
#pragma unroll
    for (int c = 0; c < RN; ++c)
      glds2(Abase + (size_t)c * BLK, ring + c * 16384 + w * 2048);
#pragma unroll
    for (int kc = 0; kc < 8; ++kc) {
      if (RN == 4) {
        if (kc <= 4) WAITVM(6);
        else if (kc == 5) WAITVM(4);
        else if (kc == 6) WAITVM(2);
        else WAITVM(0);
      } else {
        if (kc <= 5) WAITVM(4);
        else if (kc == 6) WAITVM(2);
        else WAITVM(0);
      }
      __builtin_amdgcn_s_barrier();
      if ((kc >> 2) == kh) {
        const int kcl = kc & 3;
        const unsigned char* Ab = ring + (kc % RN) * 16384;
#pragma unroll
        for (int ks = 0; ks < 4; ++ks) {
          const unsigned kb = (unsigned)ks * 64 + koff2;
#pragma unroll
          for (int rb = 0; rb < 4; ++rb) {
            const unsigned r0 = (unsigned)(rb * 16 + fr);
            bf16x8 a0 = *(const bf16x8*)(Ab + ((r0 * 256 + kb) ^ ((r0 & 7) << 4)));
            acc[rb] = __builtin_amdgcn_mfma_f32_16x16x32_bf16(
                a0, Breg[kcl][ks], acc[rb], 0, 0, 0);
          }
        }
      }
      __builtin_amdgcn_s_barrier();
      if (kc + RN < 8)
        glds2(Abase + (size_t)(kc + RN) * BLK,
              ring + ((kc + RN) % RN) * 16384 + w * 2048);
    }
  };

  if (isSeq) {
    const int erow = tid & 63, hb2 = (tid >> 6) * 2;
    const size_t gidx = (size_t)(mb * 64 + erow) * HID_DIM + cb * 16 + hb2;
    float bI[2], bF[2], bO[2], bG[2];
#pragma unroll
    for (int j = 0; j < 2; ++j) {
      bI[j] = bp[cb * 64 + hb2 + j];
      bF[j] = bp[cb * 64 + 16 + hb2 + j];
      bO[j] = bp[cb * 64 + 32 + hb2 + j];
      bG[j] = bp[cb * 64 + 48 + hb2 + j];
    }
    float cr[2] = {0.f, 0.f};
    if (t0 > 0) { float2 c2v = *(const float2*)(cst + gidx); cr[0] = c2v.x; cr[1] = c2v.y; }

#pragma unroll 1
    for (int tt = 0; tt < WINT; ++tt) {
      const int t = t0 + tt;
#pragma unroll
      for (int kcl = 0; kcl < 4; ++kcl)
#pragma unroll
        for (int ks = 0; ks < 4; ++ks)
          asm volatile("" : "+v"(Breg[kcl][ks]));
      uint4 gxv = *(const uint4*)(gxCur + ((size_t)((tt * 4 + mb) * 64 + cb)) * 8192 +
                                  (size_t)tid * 16);
      f32x4 acc[4] = {{0.f,0.f,0.f,0.f},{0.f,0.f,0.f,0.f},
                      {0.f,0.f,0.f,0.f},{0.f,0.f,0.f,0.f}};
      if (t > 0) {
        if (w == 0) {  // wave 0: 64 lanes poll 64 per-WG flags in parallel
          unsigned int* fl = &flags[mb * 64 + lane];
          while (!__all(__hip_atomic_load(fl, __ATOMIC_RELAXED,
                                          __HIP_MEMORY_SCOPE_AGENT) >= (unsigned)t))
            __builtin_amdgcn_s_sleep(2);
          (void)__hip_atomic_load(fl, __ATOMIC_ACQUIRE,
                                  __HIP_MEMORY_SCOPE_AGENT);  // L1/L2 invalidate
        }
        __syncthreads();
        const unsigned char* hA = hring + (size_t)((t + 2) % 3) * 524288 +
                                  (size_t)(mb * 8) * BLK + w * 2048 + lane * 16;
        phases(hA, acc);
      }
      {  // exchange: kh=0 -> gates0, kh=1 -> gates1
        float* g_ = kh ? gates1 : gates0;
#pragma unroll
        for (int rb = 0; rb < 4; ++rb)
#pragma unroll
          for (int j = 0; j < 4; ++j)
            g_[(rb * 16 + rsub + j) * 65 + cg * 16 + fr] = acc[rb][j];
      }
      __syncthreads();
      float hv[2];
      {
        unsigned gu0 = gxv.x, gu1 = gxv.y, gu2 = gxv.z, gu3 = gxv.w;
#pragma unroll
        for (int j = 0; j < 2; ++j) {
          int hc = hb2 + j;
          float gx0 = j ? bfhi(gu0) : bflo(gu0);
          float gx1 = j ? bfhi(gu1) : bflo(gu1);
          float gx2 = j ? bfhi(gu2) : bflo(gu2);
          float gx3 = j ? bfhi(gu3) : bflo(gu3);
          float pi = gates0[erow * 65 + hc]      + gates1[erow * 65 + hc]      + bI[j] + gx0;
          float pf = gates0[erow * 65 + 16 + hc] + gates1[erow * 65 + 16 + hc] + bF[j] + gx1;
          float po = gates0[erow * 65 + 32 + hc] + gates1[erow * 65 + 32 + hc] + bO[j] + gx2;
          float pg = gates0[erow * 65 + 48 + hc] + gates1[erow * 65 + 48 + hc] + bG[j] + gx3;
          float ig = 1.f / (1.f + __expf(-pi));
          float fg = 1.f / (1.f + __expf(-pf));
          float og = 1.f / (1.f + __expf(-po));
          float gg = 1.f - 2.f / (1.f + __expf(2.f * pg));  // tanh
          float cn = fg * cr[j] + ig * gg;
          cr[j] = cn;
          hv[j] = og * (1.f - 2.f / (1.f + __expf(2.f * cn)));
        }
      }
      if (t < T_DIM - 1) {  // store h_t bf16-pair into slot t%3, swizzled
        int hcg = cb * 16 + hb2;
        int kc2 = hcg >> 7, kp = hcg & 127;
        unsigned byte = ((unsigned)(erow * 256 + kp * 2)) ^ ((unsigned)((erow & 7) << 4));
        unsigned pk = (unsigned)f2bf(hv[0]) | ((unsigned)f2bf(hv[1]) << 16);
        unsigned int* hd = (unsigned int*)(hring + (size_t)(t % 3) * 524288 +
                                           (size_t)(mb * 8 + kc2) * BLK + byte);
        __hip_atomic_store(hd, pk, __ATOMIC_RELAXED, __HIP_MEMORY_SCOPE_AGENT);
      }
      WAITVM(0);        // per-wave: h store drained before barrier
      __syncthreads();  // all waves done (stores + gates reads)
      if (tid == 0 && t < T_DIM - 1)  // ONE release store to own slot (no RMW)
        __hip_atomic_store(&flags[mb * 64 + cb], (unsigned)(t + 1),
                           __ATOMIC_RELEASE, __HIP_MEMORY_SCOPE_AGENT);
      if (t == T_DIM - 1) {
        *(float2*)(out + gidx) = make_float2(hv[0], hv[1]);
        *(float2*)(out + (size_t)B_DIM * HID_DIM + gidx) = make_float2(cr[0], cr[1]);
      }
    }
    if (t0 + WINT < T_DIM) *(float2*)(cst + gidx) = make_float2(cr[0], cr[1]);
  } else {
    // bulk role: fixed (cb, mb); jobs tl = 0..WINT-1 (Gx for next window)
    const int erow = tid & 63, hb2 = (tid >> 6) * 2;
#pragma unroll 1
    for (int tl = 0; tl < WINT; ++tl) {
#pragma unroll
      for (int kcl = 0; kcl < 4; ++kcl)
#pragma unroll
        for (int ks = 0; ks < 4; ++ks)
          asm volatile("" : "+v"(Breg[kcl][ks]));
      f32x4 acc[4] = {{0.f,0.f,0.f,0.f},{0.f,0.f,0.f,0.f},
                      {0.f,0.f,0.f,0.f},{0.f,0.f,0.f,0.f}};
      const unsigned char* xA = xpNext + ((size_t)((tl * 4 + mb) * 8)) * BLK +
                                w * 2048 + lane * 16;
      phases(xA, acc);
      {
        float* g_ = kh ? gates1 : gates0;
#pragma unroll
        for (int rb = 0; rb < 4; ++rb)
#pragma unroll
          for (int j = 0; j < 4; ++j)
            g_[(rb * 16 + rsub + j) * 65 + cg * 16 + fr] = acc[rb][j];
      }
      __syncthreads();
      {  // pack bf16 in epilogue-thread layout: uint4 at tid*16
        unsigned u[4];
#pragma unroll
        for (int g = 0; g < 4; ++g) {
          float lo = gates0[erow * 65 + g * 16 + hb2] + gates1[erow * 65 + g * 16 + hb2];
          float hi = gates0[erow * 65 + g * 16 + hb2 + 1] + gates1[erow * 65 + g * 16 + hb2 + 1];
          u[g] = (unsigned)f2bf(lo) | ((unsigned)f2bf(hi) << 16);
        }
        uint4 pk; pk.x = u[0]; pk.y = u[1]; pk.z = u[2]; pk.w = u[3];
        *(uint4*)(gxNext + ((size_t)((tl * 4 + mb) * 64 + cb)) * 8192 +
                  (size_t)tid * 16) = pk;
      }
      __syncthreads();
    }
  }
}

extern "C" void kernel_launch(void* const* d_in, const int* in_sizes, int n_in,
                              void* d_out, int out_size, void* d_ws, size_t ws_size,
                              hipStream_t stream) {
  (void)in_sizes; (void)n_in; (void)out_size;
  const float* x   = (const float*)d_in[0];
  const float* Wf_ = (const float*)d_in[1];
  const float* bf_ = (const float*)d_in[2];
  const float* Wi_ = (const float*)d_in[3];
  const float* bi_ = (const float*)d_in[4];
  const float* Wo_ = (const float*)d_in[5];
  const float* bo_ = (const float*)d_in[6];
  const float* Wc_ = (const float*)d_in[7];
  const float* bc_ = (const float*)d_in[8];
  float* out = (float*)d_out;
  unsigned char* ws = (unsigned char*)d_ws;

  unsigned char* Wp = ws;
  size_t off = 16777216;
  float* bp = (float*)(ws + off);                    off += 16384;
  unsigned int* flags = (unsigned int*)(ws + off);   off += 8192;
  off += 8192;  // pad
  unsigned char* hring = ws + off;                   off += 3 * 524288;
  float* cst = (float*)(ws + off);                   off += 1048576;
  unsigned char* xpw0 = ws + off;                    off += (size_t)WINT * 32 * BLK;  // 16.8 MB
  unsigned char* xpw1 = ws + off;                    off += (size_t)WINT * 32 * BLK;
  unsigned char* gxw0 = ws + off;                    off += (size_t)WINT * 256 * 8192;  // 67 MB
  unsigned char* gxw1 = ws + off;                    off += (size_t)WINT * 256 * 8192;
  if (ws_size < off) return;  // 188 MB, proven available

  prep_pack_w<<<1024, 256, 0, stream>>>(Wi_, Wf_, Wo_, Wc_, Wp);
  prep_bias<<<16, 256, 0, stream>>>(bi_, bf_, bo_, bc_, bp);
  hipMemsetAsync(flags, 0, 8192, stream);

  hipFuncSetAttribute((const void*)&lstm_fused<3>,
                      hipFuncAttributeMaxDynamicSharedMemorySize, 49152);
  hipFuncSetAttribute((const void*)&lstm_fused<4>,
                      hipFuncAttributeMaxDynamicSharedMemorySize, 65536);

  // prefill: pack + bulk for window 0 (mode 2 = bulk only, non-coop, RN=4)
  prep_pack_x_win<<<WINT * 32, 256, 0, stream>>>(x, xpw0, 0);
  lstm_fused<4><<<256, 512, 65536, stream>>>(gxw1, xpw0, Wp, bp, gxw0, hring,
                                             flags, cst, out, 0, 2);

  for (int wnd = 0; wnd < NWIN; ++wnd) {
    const int t0v = wnd * WINT;
    unsigned char* gxC = (wnd & 1) ? gxw1 : gxw0;
    unsigned char* gxN = (wnd & 1) ? gxw0 : gxw1;
    unsigned char* xpN = (wnd & 1) ? xpw0 : xpw1;
    if (wnd < NWIN - 1)
      prep_pack_x_win<<<WINT * 32, 256, 0, stream>>>(x, xpN, (wnd + 1) * WINT);

    const unsigned char* a_gc = gxC;
    const unsigned char* a_xp = xpN;
    const unsigned char* a_wp = Wp;
    const float* a_bp = bp;
    unsigned char* a_gn = gxN;
    unsigned char* a_hr = hring;
    unsigned int* a_fl = flags;
    float* a_cs = cst;
    float* a_out = out;
    int a_t0 = t0v;

    hipError_t e = hipErrorUnknown;
    if (wnd < NWIN - 1) {
      int a_mode = 0;
      void* args[] = {&a_gc, &a_xp, &a_wp, &a_bp, &a_gn, &a_hr, &a_fl, &a_cs,
                      &a_out, &a_t0, &a_mode};
      // Decide fusion by the launch itself: the coop API guarantees
      // co-residency of all 512 WGs (2/CU @ 48KB LDS) or returns an error.
      e = hipLaunchCooperativeKernel((const void*)&lstm_fused<3>, dim3(512),
                                     dim3(512), args, 49152u, stream);
    }
    if (e != hipSuccess) {
      (void)hipGetLastError();  // clear sticky error from the refused launch
      int a_mode = 1;
      void* args[] = {&a_gc, &a_xp, &a_wp, &a_bp, &a_gn, &a_hr, &a_fl, &a_cs,
                      &a_out, &a_t0, &a_mode};
      hipLaunchCooperativeKernel((const void*)&lstm_fused<4>, dim3(256),
                                 dim3(512), args, 65536u, stream);
      if (wnd < NWIN - 1)  // standalone bulk for next window (fallback path)
        lstm_fused<4><<<256, 512, 65536, stream>>>(a_gc, a_xp, a_wp, a_bp, a_gn,
                                                   a_hr, a_fl, a_cs, a_out,
                                                   a_t0, 2);
    }
  }
}

// Round 13
// 9338.165 us; speedup vs baseline: 1.5413x; 1.0429x over previous
//
#include <hip/hip_runtime.h>
#include <hip/hip_bf16.h>

#define B_DIM 256
#define T_DIM 512
#define WINT 32
#define NWIN 16
#define IN_DIM 1024
#define HID_DIM 1024
#define BLK 16384

typedef __attribute__((ext_vector_type(8))) short bf16x8;
typedef __attribute__((ext_vector_type(4))) float f32x4;

__device__ __forceinline__ unsigned short f2bf(float v) {
  unsigned int u = __float_as_uint(v);
  unsigned int r = (u + 0x7fffu + ((u >> 16) & 1u)) >> 16;
  return (unsigned short)r;
}
__device__ __forceinline__ float bflo(unsigned u) { return __uint_as_float(u << 16); }
__device__ __forceinline__ float bfhi(unsigned u) { return __uint_as_float(u & 0xffff0000u); }

typedef __attribute__((address_space(3))) unsigned int lds_uint;
typedef const __attribute__((address_space(1))) unsigned int g_uint;
__device__ __forceinline__ void gload_lds16(const void* g, void* l) {
  __builtin_amdgcn_global_load_lds((g_uint*)g, (lds_uint*)l, 16, 0, 0);
}
// sc0|sc1 (CPol 0x11): read at the coherence point, bypass L1/L2 — coherent
// h-image staging without any buffer_inv.
__device__ __forceinline__ void gload_lds16cc(const void* g, void* l) {
  __builtin_amdgcn_global_load_lds((g_uint*)g, (lds_uint*)l, 16, 0, 17);
}
// 2KB: src includes per-lane offset; dst is wave-uniform base.
__device__ __forceinline__ void glds2(const unsigned char* s, unsigned char* d) {
  gload_lds16(s, d);
  gload_lds16(s + 1024, d + 1024);
}
__device__ __forceinline__ void glds2cc(const unsigned char* s, unsigned char* d) {
  gload_lds16cc(s, d);
  gload_lds16cc(s + 1024, d + 1024);
}

#define WAITVM(N) asm volatile("s_waitcnt vmcnt(" #N ")" ::: "memory")

// ---------------------------------------------------------------------------
// Pack W (4 gates, f32 [2048][1024]) -> bf16 swizzled blocks.
// Packed col in a 64-col block: g*16 + h_in. Block (cb, kc): [col 64][k' 128],
// byte = (col*256 + k'*2) ^ ((col&7)<<4). kc 0..7 = x rows, 8..15 = h rows.
// ---------------------------------------------------------------------------
__global__ void prep_pack_w(const float* __restrict__ Wi, const float* __restrict__ Wf,
                            const float* __restrict__ Wo, const float* __restrict__ Wc,
                            unsigned char* __restrict__ Wp) {
  const int bid = blockIdx.x;          // cb*16 + kc
  const int cb = bid >> 4, kc = bid & 15;
  const int tid = threadIdx.x;
  const int col = tid & 63;
  const int g = col >> 4, h_in = col & 15;
  const int kq = tid >> 6;
  const float* W = (g == 0) ? Wi : (g == 1) ? Wf : (g == 2) ? Wo : Wc;
  const float* src = W + (size_t)(kc * 128 + kq * 32) * HID_DIM + cb * 16 + h_in;
  unsigned char* dst = Wp + (size_t)bid * BLK;
  const unsigned int xo = (unsigned int)((col & 7) << 4);
#pragma unroll
  for (int b4 = 0; b4 < 4; ++b4) {
    unsigned short u[8];
#pragma unroll
    for (int j = 0; j < 8; ++j)
      u[j] = f2bf(src[(size_t)(b4 * 8 + j) * HID_DIM]);
    uint4 pk;
    pk.x = (unsigned)u[0] | ((unsigned)u[1] << 16);
    pk.y = (unsigned)u[2] | ((unsigned)u[3] << 16);
    pk.z = (unsigned)u[4] | ((unsigned)u[5] << 16);
    pk.w = (unsigned)u[6] | ((unsigned)u[7] << 16);
    unsigned int byte = ((unsigned int)(col * 256 + kq * 64 + b4 * 16)) ^ xo;
    *(uint4*)(dst + byte) = pk;
  }
}

__global__ void prep_bias(const float* __restrict__ bi, const float* __restrict__ bf_,
                          const float* __restrict__ bo, const float* __restrict__ bc,
                          float* __restrict__ bp) {
  int p = blockIdx.x * 256 + threadIdx.x;  // 0..4095
  int cbb = p >> 6, col = p & 63, g = col >> 4, h_in = col & 15;
  const float* b = (g == 0) ? bi : (g == 1) ? bf_ : (g == 2) ? bo : bc;
  bp[p] = b[cbb * 16 + h_in];
}

// Pack one WINT-step window of x -> bf16 swizzled blocks (tw,mb,kc) = bid.
__global__ void prep_pack_x_win(const float* __restrict__ x,
                                unsigned char* __restrict__ xpw, int t0) {
  const int bid = blockIdx.x;               // (tw*4+mb)*8+kc, WINT*32 blocks
  const int kc = bid & 7, mb = (bid >> 3) & 3, tw = bid >> 5;
  const int tid = threadIdx.x;
  const int row = tid >> 2, kseg = tid & 3;
  const float* src = x + ((size_t)(mb * 64 + row) * T_DIM + (t0 + tw)) * IN_DIM +
                     kc * 128 + kseg * 32;
  unsigned char* dst = xpw + (size_t)bid * BLK;
  const unsigned int xo = (unsigned)((row & 7) << 4);
#pragma unroll
  for (int c4 = 0; c4 < 4; ++c4) {
    float4 f0 = *(const float4*)(src + c4 * 8);
    float4 f1 = *(const float4*)(src + c4 * 8 + 4);
    uint4 pk;
    pk.x = (unsigned)f2bf(f0.x) | ((unsigned)f2bf(f0.y) << 16);
    pk.y = (unsigned)f2bf(f0.z) | ((unsigned)f2bf(f0.w) << 16);
    pk.z = (unsigned)f2bf(f1.x) | ((unsigned)f2bf(f1.y) << 16);
    pk.w = (unsigned)f2bf(f1.z) | ((unsigned)f2bf(f1.w) << 16);
    *(uint4*)(dst + (((unsigned)(row * 256 + kseg * 64 + c4 * 16)) ^ xo)) = pk;
  }
}

// ---------------------------------------------------------------------------
// Fused window kernel, templated on LDS ring depth RN (RN*16KB + overlays).
// RN=3 (48KB) -> 2 blocks/CU co-residency for mode 0; RN=4 (64KB) fallback.
// mode 0: 512 WGs (0-255 seq win w, 256-511 bulk win w+1); mode 1: seq only;
// mode 2: bulk only (prefill, non-coop). 64x64 tile, 8 waves (cg cols 16,
// kh K-half), Breg[4][4]=64 VGPR pinned; A staged RN-deep LDS ring via
// global_load_lds, counted vmcnt.
// Seq h path: per-WG flag release stores + wave0 parallel poll; h staged with
// sc0|sc1 coherent-bypass loads -> NO per-step acquire/buffer_inv, so L2
// stays warm for the co-resident bulk WGs (the r12 fusion stall).
// ---------------------------------------------------------------------------
template <int RN>
__global__ __launch_bounds__(512, 2) void lstm_fused(
    const unsigned char* __restrict__ gxCur, const unsigned char* __restrict__ xpNext,
    const unsigned char* __restrict__ Wq, const float* __restrict__ bp,
    unsigned char* __restrict__ gxNext, unsigned char* hring,
    unsigned int* flags, float* cst, float* __restrict__ out,
    int t0, int mode) {
  extern __shared__ unsigned char ring[];  // RN x 16KB chunk bufs
  const int tid = threadIdx.x, lane = tid & 63, w = tid >> 6;
  const int cg = w & 3, kh = w >> 2;
  const int fr = lane & 15;
  const unsigned koff2 = (unsigned)((lane >> 4) << 4);
  const int rsub = (lane >> 4) * 4;
  const int cl = cg * 16 + fr;

  bool isSeq; int wg;
  if (mode == 0) {
    isSeq = (int)blockIdx.x < 256;
    wg = isSeq ? (int)blockIdx.x : (int)blockIdx.x - 256;
  } else {
    isSeq = (mode == 1);
    wg = (int)blockIdx.x;
  }
  const int mb = (wg >> 6) & 3, cb = wg & 63;

  bf16x8 Breg[4][4];
  {
    const int xoff = isSeq ? 8 : 0;  // h rows live at kc 8..15, x rows 0..7
#pragma unroll
    for (int kcl = 0; kcl < 4; ++kcl)
#pragma unroll
      for (int ks = 0; ks < 4; ++ks)
        Breg[kcl][ks] = *(const bf16x8*)(
            Wq + ((size_t)(cb * 16 + xoff + kh * 4 + kcl) << 14) +
            (((unsigned)cl * 256 + (unsigned)ks * 64 + koff2) ^
             ((unsigned)((cl & 7) << 4))));
#pragma unroll
    for (int kcl = 0; kcl < 4; ++kcl)
#pragma unroll
      for (int ks = 0; ks < 4; ++ks)
        asm volatile("" : "+v"(Breg[kcl][ks]));
  }

  // gates overlays: RN=4 keeps the proven 32768 split; RN=3 packs at +16640
  float* gates0 = (float*)ring;
  float* gates1 = (float*)(ring + (RN == 4 ? 32768 : 16640));

  auto phases = [&](const unsigned char* Abase, f32x4* acc, bool coh) {
#pragma unroll
    for (int c = 0; c < RN; ++c) {
      if (coh) glds2cc(Abase + (size_t)c * BLK, ring + c * 16384 + w * 2048);
      else     glds2(Abase + (size_t)c * BLK, ring + c * 16384 + w * 2048);
    }
#pragma unroll
    for (int kc = 0; kc < 8; ++kc) {
      if (RN == 4) {
        if (kc <= 4) WAITVM(6);
        else if (kc == 5) WAITVM(4);
        else if (kc == 6) WAITVM(2);
        else WAITVM(0);
      } else {
        if (kc <= 5) WAITVM(4);
        else if (kc == 6) WAITVM(2);
        else WAITVM(0);
      }
      __builtin_amdgcn_s_barrier();
      if ((kc >> 2) == kh) {
        const int kcl = kc & 3;
        const unsigned char* Ab = ring + (kc % RN) * 16384;
#pragma unroll
        for (int ks = 0; ks < 4; ++ks) {
          const unsigned kb = (unsigned)ks * 64 + koff2;
#pragma unroll
          for (int rb = 0; rb < 4; ++rb) {
            const unsigned r0 = (unsigned)(rb * 16 + fr);
            bf16x8 a0 = *(const bf16x8*)(Ab + ((r0 * 256 + kb) ^ ((r0 & 7) << 4)));
            acc[rb] = __builtin_amdgcn_mfma_f32_16x16x32_bf16(
                a0, Breg[kcl][ks], acc[rb], 0, 0, 0);
          }
        }
      }
      __builtin_amdgcn_s_barrier();
      if (kc + RN < 8) {
        if (coh) glds2cc(Abase + (size_t)(kc + RN) * BLK,
                         ring + ((kc + RN) % RN) * 16384 + w * 2048);
        else     glds2(Abase + (size_t)(kc + RN) * BLK,
                       ring + ((kc + RN) % RN) * 16384 + w * 2048);
      }
    }
  };

  if (isSeq) {
    const int erow = tid & 63, hb2 = (tid >> 6) * 2;
    const size_t gidx = (size_t)(mb * 64 + erow) * HID_DIM + cb * 16 + hb2;
    float bI[2], bF[2], bO[2], bG[2];
#pragma unroll
    for (int j = 0; j < 2; ++j) {
      bI[j] = bp[cb * 64 + hb2 + j];
      bF[j] = bp[cb * 64 + 16 + hb2 + j];
      bO[j] = bp[cb * 64 + 32 + hb2 + j];
      bG[j] = bp[cb * 64 + 48 + hb2 + j];
    }
    float cr[2] = {0.f, 0.f};
    if (t0 > 0) { float2 c2v = *(const float2*)(cst + gidx); cr[0] = c2v.x; cr[1] = c2v.y; }

#pragma unroll 1
    for (int tt = 0; tt < WINT; ++tt) {
      const int t = t0 + tt;
#pragma unroll
      for (int kcl = 0; kcl < 4; ++kcl)
#pragma unroll
        for (int ks = 0; ks < 4; ++ks)
          asm volatile("" : "+v"(Breg[kcl][ks]));
      uint4 gxv = *(const uint4*)(gxCur + ((size_t)((tt * 4 + mb) * 64 + cb)) * 8192 +
                                  (size_t)tid * 16);
      f32x4 acc[4] = {{0.f,0.f,0.f,0.f},{0.f,0.f,0.f,0.f},
                      {0.f,0.f,0.f,0.f},{0.f,0.f,0.f,0.f}};
      if (t > 0) {
        if (w == 0) {  // wave 0: 64 lanes poll 64 per-WG flags in parallel
          unsigned int* fl = &flags[mb * 64 + lane];
          while (!__all(__hip_atomic_load(fl, __ATOMIC_RELAXED,
                                          __HIP_MEMORY_SCOPE_AGENT) >= (unsigned)t))
            __builtin_amdgcn_s_sleep(2);
          __builtin_amdgcn_sched_barrier(0);  // no acquire: h loads are sc0|sc1
        }
        __syncthreads();
        const unsigned char* hA = hring + (size_t)((t + 2) % 3) * 524288 +
                                  (size_t)(mb * 8) * BLK + w * 2048 + lane * 16;
        phases(hA, acc, true);
      }
      {  // exchange: kh=0 -> gates0, kh=1 -> gates1
        float* g_ = kh ? gates1 : gates0;
#pragma unroll
        for (int rb = 0; rb < 4; ++rb)
#pragma unroll
          for (int j = 0; j < 4; ++j)
            g_[(rb * 16 + rsub + j) * 65 + cg * 16 + fr] = acc[rb][j];
      }
      __syncthreads();
      float hv[2];
      {
        unsigned gu0 = gxv.x, gu1 = gxv.y, gu2 = gxv.z, gu3 = gxv.w;
#pragma unroll
        for (int j = 0; j < 2; ++j) {
          int hc = hb2 + j;
          float gx0 = j ? bfhi(gu0) : bflo(gu0);
          float gx1 = j ? bfhi(gu1) : bflo(gu1);
          float gx2 = j ? bfhi(gu2) : bflo(gu2);
          float gx3 = j ? bfhi(gu3) : bflo(gu3);
          float pi = gates0[erow * 65 + hc]      + gates1[erow * 65 + hc]      + bI[j] + gx0;
          float pf = gates0[erow * 65 + 16 + hc] + gates1[erow * 65 + 16 + hc] + bF[j] + gx1;
          float po = gates0[erow * 65 + 32 + hc] + gates1[erow * 65 + 32 + hc] + bO[j] + gx2;
          float pg = gates0[erow * 65 + 48 + hc] + gates1[erow * 65 + 48 + hc] + bG[j] + gx3;
          float ig = 1.f / (1.f + __expf(-pi));
          float fg = 1.f / (1.f + __expf(-pf));
          float og = 1.f / (1.f + __expf(-po));
          float gg = 1.f - 2.f / (1.f + __expf(2.f * pg));  // tanh
          float cn = fg * cr[j] + ig * gg;
          cr[j] = cn;
          hv[j] = og * (1.f - 2.f / (1.f + __expf(2.f * cn)));
        }
      }
      if (t < T_DIM - 1) {  // store h_t bf16-pair into slot t%3, swizzled
        int hcg = cb * 16 + hb2;
        int kc2 = hcg >> 7, kp = hcg & 127;
        unsigned byte = ((unsigned)(erow * 256 + kp * 2)) ^ ((unsigned)((erow & 7) << 4));
        unsigned pk = (unsigned)f2bf(hv[0]) | ((unsigned)f2bf(hv[1]) << 16);
        unsigned int* hd = (unsigned int*)(hring + (size_t)(t % 3) * 524288 +
                                           (size_t)(mb * 8 + kc2) * BLK + byte);
        __hip_atomic_store(hd, pk, __ATOMIC_RELAXED, __HIP_MEMORY_SCOPE_AGENT);
      }
      WAITVM(0);        // per-wave: h store drained before barrier
      __syncthreads();  // all waves done (stores + gates reads)
      if (tid == 0 && t < T_DIM - 1)  // ONE release store to own slot (no RMW)
        __hip_atomic_store(&flags[mb * 64 + cb], (unsigned)(t + 1),
                           __ATOMIC_RELEASE, __HIP_MEMORY_SCOPE_AGENT);
      if (t == T_DIM - 1) {
        *(float2*)(out + gidx) = make_float2(hv[0], hv[1]);
        *(float2*)(out + (size_t)B_DIM * HID_DIM + gidx) = make_float2(cr[0], cr[1]);
      }
    }
    if (t0 + WINT < T_DIM) *(float2*)(cst + gidx) = make_float2(cr[0], cr[1]);
  } else {
    // bulk role: fixed (cb, mb); jobs tl = 0..WINT-1 (Gx for next window)
    const int erow = tid & 63, hb2 = (tid >> 6) * 2;
#pragma unroll 1
    for (int tl = 0; tl < WINT; ++tl) {
#pragma unroll
      for (int kcl = 0; kcl < 4; ++kcl)
#pragma unroll
        for (int ks = 0; ks < 4; ++ks)
          asm volatile("" : "+v"(Breg[kcl][ks]));
      f32x4 acc[4] = {{0.f,0.f,0.f,0.f},{0.f,0.f,0.f,0.f},
                      {0.f,0.f,0.f,0.f},{0.f,0.f,0.f,0.f}};
      const unsigned char* xA = xpNext + ((size_t)((tl * 4 + mb) * 8)) * BLK +
                                w * 2048 + lane * 16;
      phases(xA, acc, false);
      {
        float* g_ = kh ? gates1 : gates0;
#pragma unroll
        for (int rb = 0; rb < 4; ++rb)
#pragma unroll
          for (int j = 0; j < 4; ++j)
            g_[(rb * 16 + rsub + j) * 65 + cg * 16 + fr] = acc[rb][j];
      }
      __syncthreads();
      {  // pack bf16 in epilogue-thread layout: uint4 at tid*16
        unsigned u[4];
#pragma unroll
        for (int g = 0; g < 4; ++g) {
          float lo = gates0[erow * 65 + g * 16 + hb2] + gates1[erow * 65 + g * 16 + hb2];
          float hi = gates0[erow * 65 + g * 16 + hb2 + 1] + gates1[erow * 65 + g * 16 + hb2 + 1];
          u[g] = (unsigned)f2bf(lo) | ((unsigned)f2bf(hi) << 16);
        }
        uint4 pk; pk.x = u[0]; pk.y = u[1]; pk.z = u[2]; pk.w = u[3];
        *(uint4*)(gxNext + ((size_t)((tl * 4 + mb) * 64 + cb)) * 8192 +
                  (size_t)tid * 16) = pk;
      }
      __syncthreads();
    }
  }
}

extern "C" void kernel_launch(void* const* d_in, const int* in_sizes, int n_in,
                              void* d_out, int out_size, void* d_ws, size_t ws_size,
                              hipStream_t stream) {
  (void)in_sizes; (void)n_in; (void)out_size;
  const float* x   = (const float*)d_in[0];
  const float* Wf_ = (const float*)d_in[1];
  const float* bf_ = (const float*)d_in[2];
  const float* Wi_ = (const float*)d_in[3];
  const float* bi_ = (const float*)d_in[4];
  const float* Wo_ = (const float*)d_in[5];
  const float* bo_ = (const float*)d_in[6];
  const float* Wc_ = (const float*)d_in[7];
  const float* bc_ = (const float*)d_in[8];
  float* out = (float*)d_out;
  unsigned char* ws = (unsigned char*)d_ws;

  unsigned char* Wp = ws;
  size_t off = 16777216;
  float* bp = (float*)(ws + off);                    off += 16384;
  unsigned int* flags = (unsigned int*)(ws + off);   off += 8192;
  off += 8192;  // pad
  unsigned char* hring = ws + off;                   off += 3 * 524288;
  float* cst = (float*)(ws + off);                   off += 1048576;
  unsigned char* xpw0 = ws + off;                    off += (size_t)WINT * 32 * BLK;  // 16.8 MB
  unsigned char* xpw1 = ws + off;                    off += (size_t)WINT * 32 * BLK;
  unsigned char* gxw0 = ws + off;                    off += (size_t)WINT * 256 * 8192;  // 67 MB
  unsigned char* gxw1 = ws + off;                    off += (size_t)WINT * 256 * 8192;
  if (ws_size < off) return;  // 188 MB, proven available

  prep_pack_w<<<1024, 256, 0, stream>>>(Wi_, Wf_, Wo_, Wc_, Wp);
  prep_bias<<<16, 256, 0, stream>>>(bi_, bf_, bo_, bc_, bp);
  hipMemsetAsync(flags, 0, 8192, stream);

  hipFuncSetAttribute((const void*)&lstm_fused<3>,
                      hipFuncAttributeMaxDynamicSharedMemorySize, 49152);
  hipFuncSetAttribute((const void*)&lstm_fused<4>,
                      hipFuncAttributeMaxDynamicSharedMemorySize, 65536);

  // prefill: pack + bulk for window 0 (mode 2 = bulk only, non-coop, RN=4)
  prep_pack_x_win<<<WINT * 32, 256, 0, stream>>>(x, xpw0, 0);
  lstm_fused<4><<<256, 512, 65536, stream>>>(gxw1, xpw0, Wp, bp, gxw0, hring,
                                             flags, cst, out, 0, 2);

  for (int wnd = 0; wnd < NWIN; ++wnd) {
    const int t0v = wnd * WINT;
    unsigned char* gxC = (wnd & 1) ? gxw1 : gxw0;
    unsigned char* gxN = (wnd & 1) ? gxw0 : gxw1;
    unsigned char* xpN = (wnd & 1) ? xpw0 : xpw1;
    if (wnd < NWIN - 1)
      prep_pack_x_win<<<WINT * 32, 256, 0, stream>>>(x, xpN, (wnd + 1) * WINT);

    const unsigned char* a_gc = gxC;
    const unsigned char* a_xp = xpN;
    const unsigned char* a_wp = Wp;
    const float* a_bp = bp;
    unsigned char* a_gn = gxN;
    unsigned char* a_hr = hring;
    unsigned int* a_fl = flags;
    float* a_cs = cst;
    float* a_out = out;
    int a_t0 = t0v;

    hipError_t e = hipErrorUnknown;
    if (wnd < NWIN - 1) {
      int a_mode = 0;
      void* args[] = {&a_gc, &a_xp, &a_wp, &a_bp, &a_gn, &a_hr, &a_fl, &a_cs,
                      &a_out, &a_t0, &a_mode};
      // Coop API guarantees co-residency of all 512 WGs (2/CU) or errors.
      e = hipLaunchCooperativeKernel((const void*)&lstm_fused<3>, dim3(512),
                                     dim3(512), args, 49152u, stream);
    }
    if (e != hipSuccess) {
      (void)hipGetLastError();  // clear sticky error from the refused launch
      int a_mode = 1;
      void* args[] = {&a_gc, &a_xp, &a_wp, &a_bp, &a_gn, &a_hr, &a_fl, &a_cs,
                      &a_out, &a_t0, &a_mode};
      hipLaunchCooperativeKernel((const void*)&lstm_fused<4>, dim3(256),
                                 dim3(512), args, 65536u, stream);
      if (wnd < NWIN - 1)  // standalone bulk for next window (fallback path)
        lstm_fused<4><<<256, 512, 65536, stream>>>(a_gc, a_xp, a_wp, a_bp, a_gn,
                                                   a_hr, a_fl, a_cs, a_out,
                                                   a_t0, 2);
    }
  }
}